// Round 1
// 1219.460 us; speedup vs baseline: 1.0460x; 1.0460x over previous
//
#include <hip/hip_runtime.h>

typedef unsigned short u16;
typedef unsigned int u32;
typedef __attribute__((ext_vector_type(8))) short bf16x8;
typedef __attribute__((ext_vector_type(4))) float f32x4;

#define N_NODES 20000
#define N_EDGES 160000
#define DDIM    1000
#define KP      1024            // padded K / row stride (elements)
#define SP      41200000        // node-buffer spacing (bytes)
#define WCAT_L  6291456         // per-layer wcat elems = 3*1024*2048

__device__ __forceinline__ float b2f(u16 u) {
    union { u32 i; float f; } v; v.i = ((u32)u) << 16; return v.f;
}
__device__ __forceinline__ u16 f2b(float f) {
    union { float f; u32 i; } v; v.f = f;
    u32 r = v.i + 0x7FFFu + ((v.i >> 16) & 1u);
    return (u16)(r >> 16);
}
__device__ __forceinline__ u32 pack2(float a, float b) {
    return (u32)f2b(a) | ((u32)f2b(b) << 16);
}
__device__ __forceinline__ f32x4 mfma16(bf16x8 a, bf16x8 b, f32x4 c) {
    return __builtin_amdgcn_mfma_f32_16x16x32_bf16(a, b, c, 0, 0, 0);
}
// fast transcendentals: v_exp_f32 / v_rcp_f32 (approx err << bf16 rounding)
__device__ __forceinline__ float fexp_(float x) {
    return __builtin_amdgcn_exp2f(x * 1.4426950408889634f);
}
__device__ __forceinline__ float fsigmoid_(float x) {
    return __builtin_amdgcn_rcpf(1.0f + fexp_(-x));   // x->-inf: rcp(inf)=0 ok
}
__device__ __forceinline__ float ftanh_(float x) {
    float ax = fabsf(x);
    float e = fexp_(-2.0f * ax);                       // e in (0,1], no overflow
    float t = (1.0f - e) * __builtin_amdgcn_rcpf(1.0f + e);
    return x >= 0.0f ? t : -t;
}

// async global->LDS DMA, 16 B per lane; lds dest = wave-uniform base + lane*16
__device__ __forceinline__ void gl2lds16(const u16* g, u16* l) {
    __builtin_amdgcn_global_load_lds(
        (const __attribute__((address_space(1))) u32*)g,
        (__attribute__((address_space(3))) u32*)l, 16, 0, 0);
}

// ---------------------------------------------------------------------------
// fp32 [rows][1000] -> bf16 [rows][1024], zero-padded cols. One block per row.
// ---------------------------------------------------------------------------
__global__ __launch_bounds__(256) void cvt_rows(const float* __restrict__ in,
                                                u16* __restrict__ out) {
    int r = blockIdx.x, c = threadIdx.x * 4;
    u32 o[2] = {0, 0};
    if (c < DDIM) {
        float4 v = *(const float4*)(in + (size_t)r * DDIM + c);
        o[0] = pack2(v.x, v.y); o[1] = pack2(v.z, v.w);
    }
    *(uint2*)(out + (size_t)r * KP + c) = *(const uint2*)o;
}

// ---------------------------------------------------------------------------
// Merged weight conversions (one dispatch, grid 15000):
//   b in [0,3000):      wih row b        -> wihb [3072][1024] (stride KP)
//   b in [3000,6000):   W row (b-3000)   -> Wb3 [3][1024][1024]
//   b in [6000,15000):  whh row, layer l -> wcat_l phase-2 half (+1024)
// All k-pads (c>=1000) written zero.
// ---------------------------------------------------------------------------
__global__ __launch_bounds__(256) void cvt_weights(const float* __restrict__ wih,
                                                   const float* __restrict__ W,
                                                   const float* __restrict__ whh,
                                                   u16* __restrict__ wihb,
                                                   u16* __restrict__ Wb3,
                                                   u16* __restrict__ wcat) {
    int b = blockIdx.x, c = threadIdx.x * 4;
    const float* src;
    u16* dst;
    if (b < 3000) {
        src = wih + (size_t)b * DDIM;
        dst = wihb + (size_t)b * KP;
    } else if (b < 6000) {
        int r = b - 3000;                    // 0..2999 = l*1000 + row
        int l = r / 1000, row = r - l * 1000;
        src = W + (size_t)r * DDIM;
        dst = Wb3 + (size_t)l * 1048576 + (size_t)row * KP;
    } else {
        int r = b - 6000;                    // 0..8999: l = r/3000, gr = r%3000
        int l = r / 3000, gr = r - l * 3000;
        int g = gr / 1000, n2 = gr - g * 1000;
        src = whh + (size_t)gr * DDIM;
        dst = wcat + (size_t)l * WCAT_L + ((size_t)g * 1024 + n2) * 2048 + 1024;
    }
    u32 o[2] = {0, 0};
    if (c < DDIM) {
        float4 v = *(const float4*)(src + c);
        o[0] = pack2(v.x, v.y); o[1] = pack2(v.z, v.w);
    }
    *(uint2*)(dst + c) = *(const uint2*)o;
}

// ---------------------------------------------------------------------------
// CSR build (edge list constant): count -> scan -> fill
// ---------------------------------------------------------------------------
__global__ __launch_bounds__(256) void count_edges(const int* __restrict__ ei,
                                                   int* __restrict__ cnt) {
    int e = blockIdx.x * 256 + threadIdx.x;
    if (e < N_EDGES) atomicAdd(&cnt[ei[N_EDGES + e]], 1);
}

__global__ __launch_bounds__(1024) void scan_offsets(const int* __restrict__ cnt,
                                                     int* __restrict__ ofs) {
    __shared__ int s[1024];
    const int CH = 20;
    int t = threadIdx.x;
    int base = t * CH;
    int loc[CH];
    int sum = 0;
    for (int j = 0; j < CH; j++) {
        int i = base + j;
        loc[j] = sum;
        sum += (i < N_NODES) ? cnt[i] : 0;
    }
    s[t] = sum;
    __syncthreads();
    for (int d = 1; d < 1024; d <<= 1) {
        int v = (t >= d) ? s[t - d] : 0;
        __syncthreads();
        s[t] += v;
        __syncthreads();
    }
    int excl = s[t] - sum;
    for (int j = 0; j < CH; j++) {
        int i = base + j;
        if (i < N_NODES) ofs[i] = excl + loc[j];
    }
    if (t == 0) ofs[N_NODES] = N_EDGES;
}

__global__ __launch_bounds__(256) void fill_buckets(const int* __restrict__ ei,
                                                    const int* __restrict__ ofs,
                                                    int* __restrict__ cur,
                                                    int* __restrict__ bkt) {
    int e = blockIdx.x * 256 + threadIdx.x;
    if (e >= N_EDGES) return;
    int d = ei[N_EDGES + e];
    int pos = atomicAdd(&cur[d], 1);
    bkt[ofs[d] + pos] = e;
}

// ---------------------------------------------------------------------------
// t[node] = sum_{e: dst=node} h[src(e)] * ew[e] — TWO nodes per block
// (half = tid>>7), uint4 gathers (125 lanes x 16 B = one 2 KB row / edge).
// Sum order per element identical to the 1-node version (bitwise-same agg).
// Threads 125..127 of each half zero k-pad cols 1000..1023.
// ---------------------------------------------------------------------------
__global__ __launch_bounds__(256) void node_agg(const int* __restrict__ ei,
                                                const float* __restrict__ ew,
                                                const int* __restrict__ ofs,
                                                const int* __restrict__ bkt,
                                                const u16* __restrict__ hsrc,
                                                u16* __restrict__ agg) {
    __shared__ int   s_src[2][32];
    __shared__ float s_w[2][32];
    __shared__ int   s_it[2];
    int tid = threadIdx.x;
    int half = tid >> 7, t = tid & 127;
    int node = blockIdx.x * 2 + half;        // grid 10000 -> nodes 0..19999
    int beg = ofs[node], end = ofs[node + 1];
    if (t == 0) s_it[half] = (end - beg + 31) >> 5;
    __syncthreads();
    int iters = max(s_it[0], s_it[1]);
    float acc[8] = {};
    for (int it = 0; it < iters; it++) {
        int cb = beg + it * 32;
        int n = min(32, end - cb);           // may be <= 0 for the short half
        if (t < n) {
            int e = bkt[cb + t];
            s_src[half][t] = ei[e];
            s_w[half][t]   = ew[e];
        }
        __syncthreads();
        if (t < 125) {
            for (int j = 0; j < n; j++) {
                int src = s_src[half][j];
                float w = s_w[half][j];
                uint4 v = *(const uint4*)(hsrc + (size_t)src * KP + t * 8);
                const u16* p = (const u16*)&v;
#pragma unroll
                for (int k = 0; k < 8; k++) acc[k] += b2f(p[k]) * w;
            }
        }
        __syncthreads();
    }
    if (t < 125) {
        u32 o[4] = {pack2(acc[0], acc[1]), pack2(acc[2], acc[3]),
                    pack2(acc[4], acc[5]), pack2(acc[6], acc[7])};
        *(uint4*)(agg + (size_t)node * KP + t * 8) = *(const uint4*)o;
    } else if (t < 128) {                    // zero pad cols 1000..1023
        uint4 z = {0, 0, 0, 0};
        *(uint4*)(agg + (size_t)node * KP + 1000 + (t - 125) * 8) = z;
    }
}

// ---------------------------------------------------------------------------
// Wc precompute: Wc_l[g, din] = sum_dout wihb[g][dout] * Wb3_l[din][dout]
// -> written into phase-1 half of wcat_l (slab = g/1000, row = g%1000).
// 128x128 tile, BK=64, XOR-swizzled staging. grid (192, 3).
// ---------------------------------------------------------------------------
__global__ __launch_bounds__(256) void gemm_wc(const u16* __restrict__ A,
                                               const u16* __restrict__ Bt3,
                                               u16* __restrict__ wcat) {
    __shared__ u16 S[16384];             // Sa [128][64] @0, Sb @8192 (u16 idx)
    int tid = threadIdx.x;
    int lane = tid & 63, wave = tid >> 6;
    int wr = wave >> 1, wc = wave & 1;
    int bid = blockIdx.x;
    int l = blockIdx.y;
    int m0 = (bid >> 3) * 128, n0 = (bid & 7) * 128;
    const u16* Bt = Bt3 + (size_t)l * 1048576;

    int aoff[4], boff[4];
#pragma unroll
    for (int i = 0; i < 4; i++) {
        int c = tid + 256 * i;
        int row = c >> 3, sl = c & 7;
        int kc = sl ^ (row & 7);
        aoff[i] = (m0 + row) * KP + kc * 8;
        boff[i] = (n0 + row) * KP + kc * 8;
    }
    f32x4 acc[4][4] = {};
    int fr = lane & 15, q = lane >> 4, sw = fr & 7;

    for (int k0 = 0; k0 < KP; k0 += 64) {
#pragma unroll
        for (int i = 0; i < 4; i++) {
            gl2lds16(A + aoff[i] + k0, &S[tid * 8 + 2048 * i]);
            gl2lds16(Bt + boff[i] + k0, &S[8192 + tid * 8 + 2048 * i]);
        }
        __syncthreads();
#pragma unroll
        for (int ks = 0; ks < 2; ks++) {
            int kx = ((ks * 4 + q) ^ sw) * 8;
            bf16x8 af[4], bf[4];
#pragma unroll
            for (int i = 0; i < 4; i++)
                af[i] = *(const bf16x8*)&S[(wr * 64 + i * 16 + fr) * 64 + kx];
#pragma unroll
            for (int j = 0; j < 4; j++)
                bf[j] = *(const bf16x8*)&S[8192 + (wc * 64 + j * 16 + fr) * 64 + kx];
#pragma unroll
            for (int i = 0; i < 4; i++)
#pragma unroll
                for (int j = 0; j < 4; j++)
                    acc[i][j] = mfma16(af[i], bf[j], acc[i][j]);
        }
        __syncthreads();
    }

    u16* wl = wcat + (size_t)l * WCAT_L;
    int cc = lane & 15, r4 = q * 4;
#pragma unroll
    for (int i = 0; i < 4; i++)
#pragma unroll
        for (int j = 0; j < 4; j++) {
            int gn = n0 + wc * 64 + j * 16 + cc;     // din column
            if (gn >= DDIM) continue;
#pragma unroll
            for (int r = 0; r < 4; r++) {
                int gm = m0 + wr * 64 + i * 16 + r4 + r;   // gate row 0..3071
                if (gm >= 3000) continue;
                int slab = (gm >= 2000) ? 2 : (gm >= 1000 ? 1 : 0);
                int row = gm - slab * 1000;
                wl[(size_t)slab * 2097152 + (size_t)row * 2048 + gn] =
                    f2b(acc[i][j][r]);
            }
        }
}

// ---------------------------------------------------------------------------
// Fused GRU, stacked-K, 8-phase-class schedule (T2+T3+T4+T5):
//   BM=256 rows, 64 gate-cols, 4 gate accumulators (r,z,n,h) = BN_eff 256.
//   512 threads / 8 waves; wave w owns rows w*32..+31, all 64 cols, all gates
//   -> acc = 128 f32/thread (register corner preserved).
//   K = 2048 = 32 tiles of BK=64: tiles 0..15 A=agg (n-gate -> aN),
//   tiles 16..31 A=h (n-gate -> aH). wcat rows are K-contiguous over both.
//   LDS 144 KB dynamic: A triple-buffered 3x[256][64] (32 KB each),
//   W double-buffered 2x[3][64][64] (24 KB each). 1 block/CU, 2 waves/SIMD.
//   Per tile, 3 phases (R/Z/NH) x 16 MFMA, each: ds-reads -> stage-issue ->
//   s_barrier -> setprio(1) MFMA setprio(0) -> s_barrier. Staging: phase R
//   issues W(t+1) (3 loads), phases Z/NH issue A(t+2) (2+2 loads). Tile
//   boundary waits COUNTED vmcnt(4) (A(t+2) stays in flight) — never 0 in
//   the main loop (drain-0 ≈ old __syncthreads structure, the 35% ceiling).
//   Raw s_barrier (not __syncthreads) so the compiler can't inject vmcnt(0).
//   XOR swizzle identical to previous kernel (bank-conflict-free, proven).
//   hi INNER in the s index: the 2 n-slices per XCD cover the SAME A-panel
//   in adjacent blocks -> partner block's A reads hit the XCD L2.
// ---------------------------------------------------------------------------
__global__ __launch_bounds__(512, 2) void gru_fused(const u16* __restrict__ agg,
                                                    const u16* __restrict__ h,
                                                    const u16* __restrict__ wcat,
                                                    const float* __restrict__ bih,
                                                    const float* __restrict__ bhh,
                                                    u16* __restrict__ hout) {
    extern __shared__ u16 S[];   // A: 3x16384 @0/16384/32768 ; W: 2x12288 @49152/61440
    int tid = threadIdx.x;
    int lane = tid & 63, wave = tid >> 6;

    int bid = blockIdx.x;                 // grid 1264 = 8 xcd x (79 panels x 2 hi)
    int xcd = bid & 7;
    int s = bid >> 3;                     // 0..157
    int panel = s >> 1, hi = s & 1;
    int m0 = panel * 256;                 // rows >= 20000: finite garbage, masked
    int n0 = (xcd * 2 + hi) * 64;

    // staging maps (XOR swizzle): slot c (row=c>>3, sl=c&7), kc = sl^(row&7)
    int aoff[4];
#pragma unroll
    for (int i = 0; i < 4; i++) {
        int c = tid + 512 * i;            // 0..2047: A rows 0..255
        int row = c >> 3, sl = c & 7;
        int kc = sl ^ (row & 7);
        aoff[i] = (m0 + row) * KP + kc * 8;
    }
    int wrow = tid >> 3;                  // 0..63
    int woff = (n0 + wrow) * 2048 + ((tid & 7) ^ (wrow & 7)) * 8;

    f32x4 aR[2][4] = {}, aZ[2][4] = {}, aN[2][4] = {}, aH[2][4] = {};
    int fr = lane & 15, q = lane >> 4, sw = fr & 7;
    int arow = (wave * 32 + fr) * 64;     // wave's A row base (elems)
    int wfr = fr * 64;
    int kx0 = (q ^ sw) * 8, kx1 = ((4 + q) ^ sw) * 8;

#define STAGE_W(ts, wb) do {                                                  \
        int kw_ = (ts) * 64;                                                  \
        _Pragma("unroll")                                                     \
        for (int g_ = 0; g_ < 3; g_++)                                        \
            gl2lds16(wcat + (size_t)g_ * 2097152 + woff + kw_,                \
                     &S[49152 + (wb) * 12288 + g_ * 4096 + tid * 8]);         \
    } while (0)

#define STAGE_A2(ts, ab, r0) do {                                             \
        const u16* ap_ = ((ts) < 16) ? agg : h;                               \
        int kb_ = ((ts) < 16) ? (ts) * 64 : (ts) * 64 - 1024;                 \
        _Pragma("unroll")                                                     \
        for (int i_ = (r0); i_ < (r0) + 2; i_++)                              \
            gl2lds16(ap_ + aoff[i_] + kb_,                                    \
                     &S[(ab) * 16384 + tid * 8 + 4096 * i_]);                 \
    } while (0)

#define READ_WF(g_) do {                                                      \
        _Pragma("unroll")                                                     \
        for (int j_ = 0; j_ < 4; j_++) {                                      \
            wf[j_][0] = *(const bf16x8*)&S[Wb + (g_) * 4096 + wfr + j_ * 1024 + kx0]; \
            wf[j_][1] = *(const bf16x8*)&S[Wb + (g_) * 4096 + wfr + j_ * 1024 + kx1]; \
        }                                                                     \
    } while (0)

#define MFMA_PH(ACC) do {                                                     \
        __builtin_amdgcn_s_setprio(1);                                        \
        _Pragma("unroll")                                                     \
        for (int i_ = 0; i_ < 2; i_++)                                        \
            _Pragma("unroll")                                                 \
            for (int j_ = 0; j_ < 4; j_++) {                                  \
                ACC[i_][j_] = mfma16(af[i_][0], wf[j_][0], ACC[i_][j_]);      \
                ACC[i_][j_] = mfma16(af[i_][1], wf[j_][1], ACC[i_][j_]);      \
            }                                                                 \
        __builtin_amdgcn_s_setprio(0);                                        \
    } while (0)

    // prologue: A(0)[4] W(0)[3] A(1)[4]; retire A(0)+W(0), leave A(1) in flight
    STAGE_A2(0, 0, 0); STAGE_A2(0, 0, 2);
    STAGE_W(0, 0);
    STAGE_A2(1, 1, 0); STAGE_A2(1, 1, 2);
    asm volatile("s_waitcnt vmcnt(4)" ::: "memory");
    __builtin_amdgcn_s_barrier();

    int abuf = 0;                         // A slot of tile t (t % 3)
#pragma unroll 1
    for (int t = 0; t < 32; t++) {
        int Ab = abuf * 16384;
        int Wb = 49152 + (t & 1) * 12288;
        bf16x8 af[2][2], wf[4][2];
        // ---- phase R: A frags (kept live all tile) + W_r; stage W(t+1) ----
#pragma unroll
        for (int i_ = 0; i_ < 2; i_++) {
            af[i_][0] = *(const bf16x8*)&S[Ab + arow + i_ * 1024 + kx0];
            af[i_][1] = *(const bf16x8*)&S[Ab + arow + i_ * 1024 + kx1];
        }
        READ_WF(0);
        if (t <= 30) STAGE_W(t + 1, (t + 1) & 1);
        __builtin_amdgcn_s_barrier();
        MFMA_PH(aR);
        __builtin_amdgcn_s_barrier();
        // ---- phase Z: W_z; stage A(t+2) rounds 0-1 ----
        READ_WF(1);
        int anext = abuf + 2; if (anext >= 3) anext -= 3;
        if (t <= 29) STAGE_A2(t + 2, anext, 0);
        __builtin_amdgcn_s_barrier();
        MFMA_PH(aZ);
        __builtin_amdgcn_s_barrier();
        // ---- phase NH: W_n; stage A(t+2) rounds 2-3; counted boundary ----
        READ_WF(2);
        if (t <= 29) STAGE_A2(t + 2, anext, 2);
        __builtin_amdgcn_s_barrier();
        if (t < 16) MFMA_PH(aN); else MFMA_PH(aH);
        // boundary: retire W(t+1)+A(t+1), leave A(t+2) (4 loads) in flight
        if (t <= 29)      asm volatile("s_waitcnt vmcnt(4)" ::: "memory");
        else if (t == 30) asm volatile("s_waitcnt vmcnt(0)" ::: "memory");
        __builtin_amdgcn_s_barrier();
        abuf++; if (abuf == 3) abuf = 0;
    }
#undef STAGE_W
#undef STAGE_A2
#undef READ_WF
#undef MFMA_PH

    // epilogue: gate math + h blend (same numerics as previous kernel)
    int cc = lane & 15, r4 = q * 4;
#pragma unroll
    for (int j = 0; j < 4; j++) {
        int gn = n0 + j * 16 + cc;
        if (gn >= DDIM) continue;
        float br  = bih[gn] + bhh[gn];
        float bz  = bih[1000 + gn] + bhh[1000 + gn];
        float bni = bih[2000 + gn];
        float bnh = bhh[2000 + gn];
#pragma unroll
        for (int i = 0; i < 2; i++)
#pragma unroll
            for (int r = 0; r < 4; r++) {
                int gm = m0 + wave * 32 + i * 16 + r4 + r;
                if (gm >= N_NODES) continue;
                float rg = fsigmoid_(aR[i][j][r] + br);
                float zg = fsigmoid_(aZ[i][j][r] + bz);
                float ng = ftanh_(aN[i][j][r] + bni + rg * (aH[i][j][r] + bnh));
                size_t idx = (size_t)gm * KP + gn;
                float hp = b2f(h[idx]);
                hout[idx] = f2b((1.0f - zg) * ng + zg * hp);
            }
    }
}

// ---------------------------------------------------------------------------
// out[row] (fp32) = relu(h[row]) . fc_w + fc_b — one wave per row, uint4 loads
// ---------------------------------------------------------------------------
__global__ __launch_bounds__(256) void fc_out(const u16* __restrict__ h,
                                              const float* __restrict__ fw,
                                              const float* __restrict__ fb,
                                              float* __restrict__ out) {
    int row = blockIdx.x * 4 + (threadIdx.x >> 6);
    int lane = threadIdx.x & 63;
    if (row >= N_NODES) return;
    float s = 0.0f;
#pragma unroll
    for (int i = 0; i < 2; i++) {
        int c = lane + 64 * i;               // chunk of 8 elems
        if (c < 125) {
            uint4 v = *(const uint4*)(h + (size_t)row * KP + c * 8);
            const u16* pv = (const u16*)&v;
            float4 w0 = *(const float4*)(fw + c * 8);
            float4 w1 = *(const float4*)(fw + c * 8 + 4);
            const float* wp = (const float*)&w0;
            float hv;
#pragma unroll
            for (int k = 0; k < 4; k++) {
                hv = b2f(pv[k]);
                s += (hv > 0.0f ? hv : 0.0f) * wp[k];
            }
            wp = (const float*)&w1;
#pragma unroll
            for (int k = 0; k < 4; k++) {
                hv = b2f(pv[4 + k]);
                s += (hv > 0.0f ? hv : 0.0f) * wp[k];
            }
        }
    }
    for (int off = 32; off > 0; off >>= 1) s += __shfl_down(s, off, 64);
    if (lane == 0) out[row] = s + fb[0];
}

// ---------------------------------------------------------------------------
extern "C" void kernel_launch(void* const* d_in, const int* in_sizes, int n_in,
                              void* d_out, int out_size, void* d_ws, size_t ws_size,
                              hipStream_t stream) {
    const float* x   = (const float*)d_in[0];
    const int*   ei  = (const int*)d_in[1];
    const float* ew  = (const float*)d_in[2];
    const float* W   = (const float*)d_in[3];
    const float* wih = (const float*)d_in[4];
    const float* whh = (const float*)d_in[5];
    const float* bih = (const float*)d_in[6];
    const float* bhh = (const float*)d_in[7];
    const float* fw  = (const float*)d_in[8];
    const float* fb  = (const float*)d_in[9];
    float* out = (float*)d_out;

    // allow 144 KB dynamic LDS for gru_fused (idempotent, not a stream op)
    hipFuncSetAttribute((const void*)gru_fused,
                        hipFuncAttributeMaxDynamicSharedMemorySize, 147456);

    // workspace (~163 MB)
    char* ws = (char*)d_ws;
    u16* xb   = (u16*)(ws);                    // [20096][1024] bf16
    u16* bufA = (u16*)(ws + (size_t)SP);       // h rotation / setup scratch
    u16* bufB = (u16*)(ws + (size_t)2 * SP);   // t (aggregate)
    u16* wcat = (u16*)(ws + 123600000);        // 37.75 MB [3][3][1024][2048]
    int* cnt  = (int*)(ws + 161400000);        // 80 KB   (cur adjacent)
    int* cur  = (int*)(ws + 161480000);        // 80 KB
    int* ofs  = (int*)(ws + 161560000);        // 80 KB + 4
    int* bkt  = (int*)(ws + 161640192);        // 640 KB

    // setup scratch inside bufA (free until layer-0 gru output)
    u16* wihb = bufA;                          // [3072][1024] (rows>=3000 junk ok)
    u16* Wb3  = bufA + 3145728;                // [3][1024][1024] (rows>=1000 junk ok)

    // one-time conversions + Wc precompute + CSR build.
    // No wcat memset: k-pad cols of valid outputs always multiply a ZERO A-pad
    // (cvt_rows / node_agg write zero pads; 0xAA poison is finite bf16), and
    // garbage weight ROWS feed only gn>=1000 outputs which epilogues discard.
    cvt_rows<<<N_NODES, 256, 0, stream>>>(x, xb);
    cvt_weights<<<15000, 256, 0, stream>>>(wih, W, whh, wihb, Wb3, wcat);
    gemm_wc<<<dim3(192, 3), 256, 0, stream>>>(wihb, Wb3, wcat);
    hipMemsetAsync(cnt, 0, 160000, stream);    // cnt + cur (contiguous)
    count_edges<<<625, 256, 0, stream>>>(ei, cnt);
    scan_offsets<<<1, 1024, 0, stream>>>(cnt, ofs);
    fill_buckets<<<625, 256, 0, stream>>>(ei, ofs, cur, bkt);

    // layer 0: t = S*x -> bufB; h1 = GRU(t, xb, wcat0) -> bufA
    node_agg<<<10000, 256, 0, stream>>>(ei, ew, ofs, bkt, xb, bufB);
    gru_fused<<<1264, 512, 147456, stream>>>(bufB, xb, wcat, bih, bhh, bufA);

    // layer 1: t = S*h1 -> bufB; h2 = GRU(t, bufA, wcat1) -> xb
    node_agg<<<10000, 256, 0, stream>>>(ei, ew, ofs, bkt, bufA, bufB);
    gru_fused<<<1264, 512, 147456, stream>>>(bufB, bufA, wcat + WCAT_L, bih, bhh, xb);

    // layer 2: t = S*h2 -> bufB; h3 = GRU(t, xb, wcat2) -> bufA
    node_agg<<<10000, 256, 0, stream>>>(ei, ew, ofs, bkt, xb, bufB);
    gru_fused<<<1264, 512, 147456, stream>>>(bufB, xb, wcat + 2 * WCAT_L, bih, bhh, bufA);

    // out = relu(h3) @ fc_w^T + fc_b
    fc_out<<<5000, 256, 0, stream>>>(bufA, fw, fb, out);
}

// Round 2
// 1094.647 us; speedup vs baseline: 1.1652x; 1.1140x over previous
//
#include <hip/hip_runtime.h>

typedef unsigned short u16;
typedef unsigned int u32;
typedef __attribute__((ext_vector_type(8))) short bf16x8;
typedef __attribute__((ext_vector_type(4))) float f32x4;

#define N_NODES 20000
#define N_EDGES 160000
#define DDIM    1000
#define KP      1024            // padded K / row stride (elements)
#define SP      41200000        // node-buffer spacing (bytes)
#define WCAT_L  6291456         // per-layer wcat elems = 3*1024*2048

__device__ __forceinline__ float b2f(u16 u) {
    union { u32 i; float f; } v; v.i = ((u32)u) << 16; return v.f;
}
__device__ __forceinline__ u16 f2b(float f) {
    union { float f; u32 i; } v; v.f = f;
    u32 r = v.i + 0x7FFFu + ((v.i >> 16) & 1u);
    return (u16)(r >> 16);
}
__device__ __forceinline__ u32 pack2(float a, float b) {
    return (u32)f2b(a) | ((u32)f2b(b) << 16);
}
__device__ __forceinline__ f32x4 mfma16(bf16x8 a, bf16x8 b, f32x4 c) {
    return __builtin_amdgcn_mfma_f32_16x16x32_bf16(a, b, c, 0, 0, 0);
}
// fast transcendentals: v_exp_f32 / v_rcp_f32 (approx err << bf16 rounding)
__device__ __forceinline__ float fexp_(float x) {
    return __builtin_amdgcn_exp2f(x * 1.4426950408889634f);
}
__device__ __forceinline__ float fsigmoid_(float x) {
    return __builtin_amdgcn_rcpf(1.0f + fexp_(-x));   // x->-inf: rcp(inf)=0 ok
}
__device__ __forceinline__ float ftanh_(float x) {
    float ax = fabsf(x);
    float e = fexp_(-2.0f * ax);                       // e in (0,1], no overflow
    float t = (1.0f - e) * __builtin_amdgcn_rcpf(1.0f + e);
    return x >= 0.0f ? t : -t;
}

// async global->LDS DMA, 16 B per lane; lds dest = wave-uniform base + lane*16
__device__ __forceinline__ void gl2lds16(const u16* g, u16* l) {
    __builtin_amdgcn_global_load_lds(
        (const __attribute__((address_space(1))) u32*)g,
        (__attribute__((address_space(3))) u32*)l, 16, 0, 0);
}

// ---------------------------------------------------------------------------
// fp32 [rows][1000] -> bf16 [rows][1024], zero-padded cols. One block per row.
// ---------------------------------------------------------------------------
__global__ __launch_bounds__(256) void cvt_rows(const float* __restrict__ in,
                                                u16* __restrict__ out) {
    int r = blockIdx.x, c = threadIdx.x * 4;
    u32 o[2] = {0, 0};
    if (c < DDIM) {
        float4 v = *(const float4*)(in + (size_t)r * DDIM + c);
        o[0] = pack2(v.x, v.y); o[1] = pack2(v.z, v.w);
    }
    *(uint2*)(out + (size_t)r * KP + c) = *(const uint2*)o;
}

// ---------------------------------------------------------------------------
// Merged weight conversions (one dispatch, grid 15000):
//   b in [0,3000):      wih row b        -> wihb [3072][1024] (stride KP)
//   b in [3000,6000):   W row (b-3000)   -> Wb3 [3][1024][1024]
//   b in [6000,15000):  whh row, layer l -> wcat_l phase-2 half (+1024)
// All k-pads (c>=1000) written zero.
// ---------------------------------------------------------------------------
__global__ __launch_bounds__(256) void cvt_weights(const float* __restrict__ wih,
                                                   const float* __restrict__ W,
                                                   const float* __restrict__ whh,
                                                   u16* __restrict__ wihb,
                                                   u16* __restrict__ Wb3,
                                                   u16* __restrict__ wcat) {
    int b = blockIdx.x, c = threadIdx.x * 4;
    const float* src;
    u16* dst;
    if (b < 3000) {
        src = wih + (size_t)b * DDIM;
        dst = wihb + (size_t)b * KP;
    } else if (b < 6000) {
        int r = b - 3000;                    // 0..2999 = l*1000 + row
        int l = r / 1000, row = r - l * 1000;
        src = W + (size_t)r * DDIM;
        dst = Wb3 + (size_t)l * 1048576 + (size_t)row * KP;
    } else {
        int r = b - 6000;                    // 0..8999: l = r/3000, gr = r%3000
        int l = r / 3000, gr = r - l * 3000;
        int g = gr / 1000, n2 = gr - g * 1000;
        src = whh + (size_t)gr * DDIM;
        dst = wcat + (size_t)l * WCAT_L + ((size_t)g * 1024 + n2) * 2048 + 1024;
    }
    u32 o[2] = {0, 0};
    if (c < DDIM) {
        float4 v = *(const float4*)(src + c);
        o[0] = pack2(v.x, v.y); o[1] = pack2(v.z, v.w);
    }
    *(uint2*)(dst + c) = *(const uint2*)o;
}

// ---------------------------------------------------------------------------
// CSR build (edge list constant): count -> scan -> fill
// ---------------------------------------------------------------------------
__global__ __launch_bounds__(256) void count_edges(const int* __restrict__ ei,
                                                   int* __restrict__ cnt) {
    int e = blockIdx.x * 256 + threadIdx.x;
    if (e < N_EDGES) atomicAdd(&cnt[ei[N_EDGES + e]], 1);
}

__global__ __launch_bounds__(1024) void scan_offsets(const int* __restrict__ cnt,
                                                     int* __restrict__ ofs) {
    __shared__ int s[1024];
    const int CH = 20;
    int t = threadIdx.x;
    int base = t * CH;
    int loc[CH];
    int sum = 0;
    for (int j = 0; j < CH; j++) {
        int i = base + j;
        loc[j] = sum;
        sum += (i < N_NODES) ? cnt[i] : 0;
    }
    s[t] = sum;
    __syncthreads();
    for (int d = 1; d < 1024; d <<= 1) {
        int v = (t >= d) ? s[t - d] : 0;
        __syncthreads();
        s[t] += v;
        __syncthreads();
    }
    int excl = s[t] - sum;
    for (int j = 0; j < CH; j++) {
        int i = base + j;
        if (i < N_NODES) ofs[i] = excl + loc[j];
    }
    if (t == 0) ofs[N_NODES] = N_EDGES;
}

__global__ __launch_bounds__(256) void fill_buckets(const int* __restrict__ ei,
                                                    const int* __restrict__ ofs,
                                                    int* __restrict__ cur,
                                                    int* __restrict__ bkt) {
    int e = blockIdx.x * 256 + threadIdx.x;
    if (e >= N_EDGES) return;
    int d = ei[N_EDGES + e];
    int pos = atomicAdd(&cur[d], 1);
    bkt[ofs[d] + pos] = e;
}

// ---------------------------------------------------------------------------
// t[node] = sum_{e: dst=node} h[src(e)] * ew[e] — TWO nodes per block
// (half = tid>>7), uint4 gathers (125 lanes x 16 B = one 2 KB row / edge).
// Sum order per element identical to the 1-node version (bitwise-same agg).
// Threads 125..127 of each half zero k-pad cols 1000..1023.
// ---------------------------------------------------------------------------
__global__ __launch_bounds__(256) void node_agg(const int* __restrict__ ei,
                                                const float* __restrict__ ew,
                                                const int* __restrict__ ofs,
                                                const int* __restrict__ bkt,
                                                const u16* __restrict__ hsrc,
                                                u16* __restrict__ agg) {
    __shared__ int   s_src[2][32];
    __shared__ float s_w[2][32];
    __shared__ int   s_it[2];
    int tid = threadIdx.x;
    int half = tid >> 7, t = tid & 127;
    int node = blockIdx.x * 2 + half;        // grid 10000 -> nodes 0..19999
    int beg = ofs[node], end = ofs[node + 1];
    if (t == 0) s_it[half] = (end - beg + 31) >> 5;
    __syncthreads();
    int iters = max(s_it[0], s_it[1]);
    float acc[8] = {};
    for (int it = 0; it < iters; it++) {
        int cb = beg + it * 32;
        int n = min(32, end - cb);           // may be <= 0 for the short half
        if (t < n) {
            int e = bkt[cb + t];
            s_src[half][t] = ei[e];
            s_w[half][t]   = ew[e];
        }
        __syncthreads();
        if (t < 125) {
            for (int j = 0; j < n; j++) {
                int src = s_src[half][j];
                float w = s_w[half][j];
                uint4 v = *(const uint4*)(hsrc + (size_t)src * KP + t * 8);
                const u16* p = (const u16*)&v;
#pragma unroll
                for (int k = 0; k < 8; k++) acc[k] += b2f(p[k]) * w;
            }
        }
        __syncthreads();
    }
    if (t < 125) {
        u32 o[4] = {pack2(acc[0], acc[1]), pack2(acc[2], acc[3]),
                    pack2(acc[4], acc[5]), pack2(acc[6], acc[7])};
        *(uint4*)(agg + (size_t)node * KP + t * 8) = *(const uint4*)o;
    } else if (t < 128) {                    // zero pad cols 1000..1023
        uint4 z = {0, 0, 0, 0};
        *(uint4*)(agg + (size_t)node * KP + 1000 + (t - 125) * 8) = z;
    }
}

// ---------------------------------------------------------------------------
// Wc precompute: Wc_l[g, din] = sum_dout wihb[g][dout] * Wb3_l[din][dout]
// -> written into phase-1 half of wcat_l (slab = g/1000, row = g%1000).
// 128x128 tile, BK=64, XOR-swizzled staging. grid (192, 3).
// ---------------------------------------------------------------------------
__global__ __launch_bounds__(256) void gemm_wc(const u16* __restrict__ A,
                                               const u16* __restrict__ Bt3,
                                               u16* __restrict__ wcat) {
    __shared__ u16 S[16384];             // Sa [128][64] @0, Sb @8192 (u16 idx)
    int tid = threadIdx.x;
    int lane = tid & 63, wave = tid >> 6;
    int wr = wave >> 1, wc = wave & 1;
    int bid = blockIdx.x;
    int l = blockIdx.y;
    int m0 = (bid >> 3) * 128, n0 = (bid & 7) * 128;
    const u16* Bt = Bt3 + (size_t)l * 1048576;

    int aoff[4], boff[4];
#pragma unroll
    for (int i = 0; i < 4; i++) {
        int c = tid + 256 * i;
        int row = c >> 3, sl = c & 7;
        int kc = sl ^ (row & 7);
        aoff[i] = (m0 + row) * KP + kc * 8;
        boff[i] = (n0 + row) * KP + kc * 8;
    }
    f32x4 acc[4][4] = {};
    int fr = lane & 15, q = lane >> 4, sw = fr & 7;

    for (int k0 = 0; k0 < KP; k0 += 64) {
#pragma unroll
        for (int i = 0; i < 4; i++) {
            gl2lds16(A + aoff[i] + k0, &S[tid * 8 + 2048 * i]);
            gl2lds16(Bt + boff[i] + k0, &S[8192 + tid * 8 + 2048 * i]);
        }
        __syncthreads();
#pragma unroll
        for (int ks = 0; ks < 2; ks++) {
            int kx = ((ks * 4 + q) ^ sw) * 8;
            bf16x8 af[4], bf[4];
#pragma unroll
            for (int i = 0; i < 4; i++)
                af[i] = *(const bf16x8*)&S[(wr * 64 + i * 16 + fr) * 64 + kx];
#pragma unroll
            for (int j = 0; j < 4; j++)
                bf[j] = *(const bf16x8*)&S[8192 + (wc * 64 + j * 16 + fr) * 64 + kx];
#pragma unroll
            for (int i = 0; i < 4; i++)
#pragma unroll
                for (int j = 0; j < 4; j++)
                    acc[i][j] = mfma16(af[i], bf[j], acc[i][j]);
        }
        __syncthreads();
    }

    u16* wl = wcat + (size_t)l * WCAT_L;
    int cc = lane & 15, r4 = q * 4;
#pragma unroll
    for (int i = 0; i < 4; i++)
#pragma unroll
        for (int j = 0; j < 4; j++) {
            int gn = n0 + wc * 64 + j * 16 + cc;     // din column
            if (gn >= DDIM) continue;
#pragma unroll
            for (int r = 0; r < 4; r++) {
                int gm = m0 + wr * 64 + i * 16 + r4 + r;   // gate row 0..3071
                if (gm >= 3000) continue;
                int slab = (gm >= 2000) ? 2 : (gm >= 1000 ? 1 : 0);
                int row = gm - slab * 1000;
                wl[(size_t)slab * 2097152 + (size_t)row * 2048 + gn] =
                    f2b(acc[i][j][r]);
            }
        }
}

// ---------------------------------------------------------------------------
// Fused GRU, stacked-K, free-running tile schedule:
//   BM=256 rows, 64 gate-cols, 4 gate accumulators (r,z,n,h) = BN_eff 256.
//   512 threads / 8 waves; wave tile = 64 rows x 32 cols (wr=wave>>1,
//   wc=wave&1) -> per tile per wave: A 8 b128 (shared by all 3 gates) +
//   W 12 b128 = 20 ds_read_b128 for 48 MFMA (was 28 at 32x64 — LDS pipe and
//   MFMA pipe are ~1:1 per-CU now). acc = 128 f32/thread.
//   K = 2048 = 32 tiles of BK=64: tiles 0..15 A=agg (n -> aN),
//   tiles 16..31 A=h (n -> aH). LDS 144 KB: A 3x16384 @0, W 2x12288 @49152.
//   ONE barrier + counted vmcnt per tile (no intra-tile barriers: reads hit
//   buffer t, staging writes t+1/t+2 — no hazard; R1 showed block-wide
//   per-phase barriers serialize LDS-read time against MFMA time, pinning
//   MfmaUtil at 35%). Compiler software-pipelines gate Z/N reads under gate
//   R MFMAs via counted lgkmcnt; waves drift within a tile -> pipe overlap.
//   Boundary: vmcnt(4) keeps A(t+2) in flight — never drains in main loop.
//   No setprio (needs role-split; per-tile realignment suppresses it, m190).
//   hi INNER in s: the 2 n-slices per XCD share the A-panel via L2 (R1:
//   FETCH 678->366 MB, keep).
// ---------------------------------------------------------------------------
__global__ __launch_bounds__(512, 2) void gru_fused(const u16* __restrict__ agg,
                                                    const u16* __restrict__ h,
                                                    const u16* __restrict__ wcat,
                                                    const float* __restrict__ bih,
                                                    const float* __restrict__ bhh,
                                                    u16* __restrict__ hout) {
    extern __shared__ u16 S[];   // A: 3x16384 @0/16384/32768 ; W: 2x12288 @49152/61440
    int tid = threadIdx.x;
    int lane = tid & 63, wave = tid >> 6;
    int wr = wave >> 1, wc = wave & 1;    // wave tile: rows wr*64.., cols wc*32..

    int bid = blockIdx.x;                 // grid 1264 = 8 xcd x (79 panels x 2 hi)
    int xcd = bid & 7;
    int s = bid >> 3;                     // 0..157
    int panel = s >> 1, hi = s & 1;
    int m0 = panel * 256;                 // rows >= 20000: finite garbage, masked
    int n0 = (xcd * 2 + hi) * 64;

    // staging maps (XOR swizzle): slot c (row=c>>3, sl=c&7), kc = sl^(row&7)
    int aoff[4];
#pragma unroll
    for (int i = 0; i < 4; i++) {
        int c = tid + 512 * i;            // 0..2047: A rows 0..255
        int row = c >> 3, sl = c & 7;
        int kc = sl ^ (row & 7);
        aoff[i] = (m0 + row) * KP + kc * 8;
    }
    int wrow = tid >> 3;                  // 0..63
    int woff = (n0 + wrow) * 2048 + ((tid & 7) ^ (wrow & 7)) * 8;

    f32x4 aR[4][2] = {}, aZ[4][2] = {}, aN[4][2] = {}, aH[4][2] = {};
    int fr = lane & 15, q = lane >> 4, sw = fr & 7;
    int kx0 = (q ^ sw) * 8, kx1 = ((4 + q) ^ sw) * 8;
    int arow[4], wcol[2];
#pragma unroll
    for (int i = 0; i < 4; i++) arow[i] = (wr * 64 + i * 16 + fr) * 64;
#pragma unroll
    for (int j = 0; j < 2; j++) wcol[j] = (wc * 32 + j * 16 + fr) * 64;

#define STAGE_W(ts, wb) do {                                                  \
        int kw_ = (ts) * 64;                                                  \
        _Pragma("unroll")                                                     \
        for (int g_ = 0; g_ < 3; g_++)                                        \
            gl2lds16(wcat + (size_t)g_ * 2097152 + woff + kw_,                \
                     &S[49152 + (wb) * 12288 + g_ * 4096 + tid * 8]);         \
    } while (0)

#define STAGE_A2(ts, ab, r0) do {                                             \
        const u16* ap_ = ((ts) < 16) ? agg : h;                               \
        int kb_ = ((ts) < 16) ? (ts) * 64 : (ts) * 64 - 1024;                 \
        _Pragma("unroll")                                                     \
        for (int i_ = (r0); i_ < (r0) + 2; i_++)                              \
            gl2lds16(ap_ + aoff[i_] + kb_,                                    \
                     &S[(ab) * 16384 + tid * 8 + 4096 * i_]);                 \
    } while (0)

#define READ_WF(g_) do {                                                      \
        _Pragma("unroll")                                                     \
        for (int j_ = 0; j_ < 2; j_++) {                                      \
            wf[j_][0] = *(const bf16x8*)&S[Wb + (g_) * 4096 + wcol[j_] + kx0];\
            wf[j_][1] = *(const bf16x8*)&S[Wb + (g_) * 4096 + wcol[j_] + kx1];\
        }                                                                     \
    } while (0)

#define MFMA_G(ACC) do {                                                      \
        _Pragma("unroll")                                                     \
        for (int i_ = 0; i_ < 4; i_++)                                        \
            _Pragma("unroll")                                                 \
            for (int j_ = 0; j_ < 2; j_++) {                                  \
                ACC[i_][j_] = mfma16(af[i_][0], wf[j_][0], ACC[i_][j_]);      \
                ACC[i_][j_] = mfma16(af[i_][1], wf[j_][1], ACC[i_][j_]);      \
            }                                                                 \
    } while (0)

    // prologue: A(0)[4] W(0)[3] A(1)[4]; retire A(0)+W(0), leave A(1) in flight
    STAGE_A2(0, 0, 0); STAGE_A2(0, 0, 2);
    STAGE_W(0, 0);
    STAGE_A2(1, 1, 0); STAGE_A2(1, 1, 2);
    asm volatile("s_waitcnt vmcnt(4)" ::: "memory");
    __builtin_amdgcn_s_barrier();

    int abuf = 0;                         // A slot of tile t (t % 3)
#pragma unroll 1
    for (int t = 0; t < 32; t++) {
        int Ab = abuf * 16384;
        int Wb = 49152 + (t & 1) * 12288;
        int anext = abuf + 2; if (anext >= 3) anext -= 3;
        bf16x8 af[4][2], wf[2][2];
        // A frags: read once, feed all 3 gates
#pragma unroll
        for (int i = 0; i < 4; i++) {
            af[i][0] = *(const bf16x8*)&S[Ab + arow[i] + kx0];
            af[i][1] = *(const bf16x8*)&S[Ab + arow[i] + kx1];
        }
        // gate R; stage W(t+1) (issue order: W x3 first)
        READ_WF(0);
        if (t <= 30) STAGE_W(t + 1, (t + 1) & 1);
        MFMA_G(aR);
        // gate Z; stage A(t+2) rounds 0-1
        READ_WF(1);
        if (t <= 29) STAGE_A2(t + 2, anext, 0);
        MFMA_G(aZ);
        // gate N (tiles 0..15) / H (16..31); stage A(t+2) rounds 2-3
        READ_WF(2);
        if (t <= 29) STAGE_A2(t + 2, anext, 2);
        if (t < 16) MFMA_G(aN); else MFMA_G(aH);
        // boundary: retire W(t+1)+A(t+1), leave A(t+2) (4 loads) in flight
        if (t <= 29)      asm volatile("s_waitcnt vmcnt(4)" ::: "memory");
        else if (t == 30) asm volatile("s_waitcnt vmcnt(0)" ::: "memory");
        __builtin_amdgcn_s_barrier();
        abuf++; if (abuf == 3) abuf = 0;
    }
#undef STAGE_W
#undef STAGE_A2
#undef READ_WF
#undef MFMA_G

    // epilogue: gate math + h blend (same numerics as previous kernel)
    int cc = lane & 15, r4 = q * 4;
#pragma unroll
    for (int j = 0; j < 2; j++) {
        int gn = n0 + wc * 32 + j * 16 + cc;
        if (gn >= DDIM) continue;
        float br  = bih[gn] + bhh[gn];
        float bz  = bih[1000 + gn] + bhh[1000 + gn];
        float bni = bih[2000 + gn];
        float bnh = bhh[2000 + gn];
#pragma unroll
        for (int i = 0; i < 4; i++)
#pragma unroll
            for (int r = 0; r < 4; r++) {
                int gm = m0 + wr * 64 + i * 16 + r4 + r;
                if (gm >= N_NODES) continue;
                float rg = fsigmoid_(aR[i][j][r] + br);
                float zg = fsigmoid_(aZ[i][j][r] + bz);
                float ng = ftanh_(aN[i][j][r] + bni + rg * (aH[i][j][r] + bnh));
                size_t idx = (size_t)gm * KP + gn;
                float hp = b2f(h[idx]);
                hout[idx] = f2b((1.0f - zg) * ng + zg * hp);
            }
    }
}

// ---------------------------------------------------------------------------
// out[row] (fp32) = relu(h[row]) . fc_w + fc_b — one wave per row, uint4 loads
// ---------------------------------------------------------------------------
__global__ __launch_bounds__(256) void fc_out(const u16* __restrict__ h,
                                              const float* __restrict__ fw,
                                              const float* __restrict__ fb,
                                              float* __restrict__ out) {
    int row = blockIdx.x * 4 + (threadIdx.x >> 6);
    int lane = threadIdx.x & 63;
    if (row >= N_NODES) return;
    float s = 0.0f;
#pragma unroll
    for (int i = 0; i < 2; i++) {
        int c = lane + 64 * i;               // chunk of 8 elems
        if (c < 125) {
            uint4 v = *(const uint4*)(h + (size_t)row * KP + c * 8);
            const u16* pv = (const u16*)&v;
            float4 w0 = *(const float4*)(fw + c * 8);
            float4 w1 = *(const float4*)(fw + c * 8 + 4);
            const float* wp = (const float*)&w0;
            float hv;
#pragma unroll
            for (int k = 0; k < 4; k++) {
                hv = b2f(pv[k]);
                s += (hv > 0.0f ? hv : 0.0f) * wp[k];
            }
            wp = (const float*)&w1;
#pragma unroll
            for (int k = 0; k < 4; k++) {
                hv = b2f(pv[4 + k]);
                s += (hv > 0.0f ? hv : 0.0f) * wp[k];
            }
        }
    }
    for (int off = 32; off > 0; off >>= 1) s += __shfl_down(s, off, 64);
    if (lane == 0) out[row] = s + fb[0];
}

// ---------------------------------------------------------------------------
extern "C" void kernel_launch(void* const* d_in, const int* in_sizes, int n_in,
                              void* d_out, int out_size, void* d_ws, size_t ws_size,
                              hipStream_t stream) {
    const float* x   = (const float*)d_in[0];
    const int*   ei  = (const int*)d_in[1];
    const float* ew  = (const float*)d_in[2];
    const float* W   = (const float*)d_in[3];
    const float* wih = (const float*)d_in[4];
    const float* whh = (const float*)d_in[5];
    const float* bih = (const float*)d_in[6];
    const float* bhh = (const float*)d_in[7];
    const float* fw  = (const float*)d_in[8];
    const float* fb  = (const float*)d_in[9];
    float* out = (float*)d_out;

    // allow 144 KB dynamic LDS for gru_fused (idempotent, not a stream op)
    hipFuncSetAttribute((const void*)gru_fused,
                        hipFuncAttributeMaxDynamicSharedMemorySize, 147456);

    // workspace (~163 MB)
    char* ws = (char*)d_ws;
    u16* xb   = (u16*)(ws);                    // [20096][1024] bf16
    u16* bufA = (u16*)(ws + (size_t)SP);       // h rotation / setup scratch
    u16* bufB = (u16*)(ws + (size_t)2 * SP);   // t (aggregate)
    u16* wcat = (u16*)(ws + 123600000);        // 37.75 MB [3][3][1024][2048]
    int* cnt  = (int*)(ws + 161400000);        // 80 KB   (cur adjacent)
    int* cur  = (int*)(ws + 161480000);        // 80 KB
    int* ofs  = (int*)(ws + 161560000);        // 80 KB + 4
    int* bkt  = (int*)(ws + 161640192);        // 640 KB

    // setup scratch inside bufA (free until layer-0 gru output)
    u16* wihb = bufA;                          // [3072][1024] (rows>=3000 junk ok)
    u16* Wb3  = bufA + 3145728;                // [3][1024][1024] (rows>=1000 junk ok)

    // one-time conversions + Wc precompute + CSR build.
    // No wcat memset: k-pad cols of valid outputs always multiply a ZERO A-pad
    // (cvt_rows / node_agg write zero pads; 0xAA poison is finite bf16), and
    // garbage weight ROWS feed only gn>=1000 outputs which epilogues discard.
    cvt_rows<<<N_NODES, 256, 0, stream>>>(x, xb);
    cvt_weights<<<15000, 256, 0, stream>>>(wih, W, whh, wihb, Wb3, wcat);
    gemm_wc<<<dim3(192, 3), 256, 0, stream>>>(wihb, Wb3, wcat);
    hipMemsetAsync(cnt, 0, 160000, stream);    // cnt + cur (contiguous)
    count_edges<<<625, 256, 0, stream>>>(ei, cnt);
    scan_offsets<<<1, 1024, 0, stream>>>(cnt, ofs);
    fill_buckets<<<625, 256, 0, stream>>>(ei, ofs, cur, bkt);

    // layer 0: t = S*x -> bufB; h1 = GRU(t, xb, wcat0) -> bufA
    node_agg<<<10000, 256, 0, stream>>>(ei, ew, ofs, bkt, xb, bufB);
    gru_fused<<<1264, 512, 147456, stream>>>(bufB, xb, wcat, bih, bhh, bufA);

    // layer 1: t = S*h1 -> bufB; h2 = GRU(t, bufA, wcat1) -> xb
    node_agg<<<10000, 256, 0, stream>>>(ei, ew, ofs, bkt, bufA, bufB);
    gru_fused<<<1264, 512, 147456, stream>>>(bufB, bufA, wcat + WCAT_L, bih, bhh, xb);

    // layer 2: t = S*h2 -> bufB; h3 = GRU(t, xb, wcat2) -> bufA
    node_agg<<<10000, 256, 0, stream>>>(ei, ew, ofs, bkt, xb, bufB);
    gru_fused<<<1264, 512, 147456, stream>>>(bufB, xb, wcat + 2 * WCAT_L, bih, bhh, bufA);

    // out = relu(h3) @ fc_w^T + fc_b
    fc_out<<<5000, 256, 0, stream>>>(bufA, fw, fb, out);
}